// Round 1
// baseline (958.851 us; speedup 1.0000x reference)
//
#include <hip/hip_runtime.h>
#include <stdint.h>

typedef __bf16 bf16x8 __attribute__((ext_vector_type(8)));
typedef float f32x4 __attribute__((ext_vector_type(4)));

#define S_LEN 2048
#define NHEADS 32
#define NKVH 8
#define HDIM 128
#define MROWS 4096        // B*S
#define LDQKV 6144        // fused QKV row stride
#define SCALE 0.08838834764831845f

__device__ __forceinline__ unsigned short f2bf(float f) {
  unsigned u = __float_as_uint(f);
  u += 0x7FFFu + ((u >> 16) & 1u);
  return (unsigned short)(u >> 16);
}
__device__ __forceinline__ float bf2f(unsigned short h) {
  return __uint_as_float(((unsigned)h) << 16);
}

__device__ __forceinline__ void gload16(const unsigned short* g, unsigned short* l) {
  __builtin_amdgcn_global_load_lds(
      (__attribute__((address_space(1))) void*)(g),
      (__attribute__((address_space(3))) void*)(l), 16, 0, 0);
}

// ---------------- fp32 -> bf16 cast, vectorized ----------------
__global__ void cast_f32_bf16(const float4* __restrict__ in, ushort4* __restrict__ out, int n4) {
  int i = blockIdx.x * 256 + threadIdx.x;
  const int stride = gridDim.x * 256;
  for (; i < n4; i += stride) {
    float4 v = in[i];
    ushort4 o;
    o.x = f2bf(v.x); o.y = f2bf(v.y); o.z = f2bf(v.z); o.w = f2bf(v.w);
    out[i] = o;
  }
}

// ---------------- GEMM: C[M,N] = A[M,K] @ Bw[N,K]^T + bias ----------------
// m97-structure: 128x128 tile, BK=32, 4 waves, global_load_lds w=16.
template <int OUTF>
__global__ __launch_bounds__(256, 2)
void gemm_bt(const unsigned short* __restrict__ A,
             const unsigned short* __restrict__ Bw,
             const float* __restrict__ bias,
             void* __restrict__ C,
             int M, int N, int K) {
  __shared__ unsigned short sA[128][32];
  __shared__ unsigned short sB[128][32];

  const int t = threadIdx.x;
  const int lane = t & 63;
  const int wave = t >> 6;
  const int wr = wave >> 1, wc = wave & 1;
  const int row16 = lane & 15, kgrp = lane >> 4;
  const int m0 = blockIdx.y * 128;
  const int n0 = blockIdx.x * 128;

  const int srow = t >> 2;
  const int scol = (t & 3) << 3;

  const unsigned short* Ap = A + (size_t)(m0 + srow) * K + scol;
  const unsigned short* Bp = Bw + (size_t)(n0 + srow) * K + scol;
  unsigned short* sAp = &sA[srow][scol];
  unsigned short* sBp = &sB[srow][scol];

  f32x4 acc[4][4];
#pragma unroll
  for (int i = 0; i < 4; i++)
#pragma unroll
    for (int j = 0; j < 4; j++) acc[i][j] = (f32x4){0.f, 0.f, 0.f, 0.f};

  for (int k0 = 0; k0 < K; k0 += 32) {
    gload16(Ap, sAp);
    gload16(Ap + (size_t)64 * K, sAp + 64 * 32);
    gload16(Bp, sBp);
    gload16(Bp + (size_t)64 * K, sBp + 64 * 32);
    Ap += 32; Bp += 32;
    asm volatile("s_waitcnt vmcnt(0)" ::: "memory");
    __syncthreads();

    bf16x8 af[4], bfr[4];
#pragma unroll
    for (int i = 0; i < 4; i++) af[i] = *(const bf16x8*)&sA[wr * 64 + i * 16 + row16][kgrp * 8];
#pragma unroll
    for (int j = 0; j < 4; j++) bfr[j] = *(const bf16x8*)&sB[wc * 64 + j * 16 + row16][kgrp * 8];
#pragma unroll
    for (int i = 0; i < 4; i++)
#pragma unroll
      for (int j = 0; j < 4; j++)
        acc[i][j] = __builtin_amdgcn_mfma_f32_16x16x32_bf16(af[i], bfr[j], acc[i][j], 0, 0, 0);
    __syncthreads();
  }

#pragma unroll
  for (int i = 0; i < 4; i++) {
#pragma unroll
    for (int j = 0; j < 4; j++) {
      const int gr = m0 + wr * 64 + i * 16 + kgrp * 4;
      const int gc = n0 + wc * 64 + j * 16 + row16;
      const float bv = bias[gc];
#pragma unroll
      for (int jj = 0; jj < 4; jj++) {
        float v = acc[i][j][jj] + bv;
        if (OUTF) ((float*)C)[(size_t)(gr + jj) * N + gc] = v;
        else ((unsigned short*)C)[(size_t)(gr + jj) * N + gc] = f2bf(v);
      }
    }
  }
}

// ---------------- RoPE (interleaved), in-place on bf16, row stride ld ----------------
__global__ void rope_kernel(unsigned short* __restrict__ X,
                            const int* __restrict__ pos_ids,
                            int ncols, int ld) {
  const int perrow = ncols >> 3;
  int idx = blockIdx.x * 256 + threadIdx.x;
  const int row = idx / perrow;
  const int c0 = (idx - row * perrow) << 3;
  const float pos = (float)pos_ids[row];
  unsigned short* p = X + (size_t)row * ld + c0;
  uint4 v = *(uint4*)p;
  unsigned short* e = (unsigned short*)&v;
  const int p0 = (c0 & 127) >> 1;
#pragma unroll
  for (int q = 0; q < 4; ++q) {
    const float inv = exp2f(-(float)(p0 + q) * (19.931568569324174f / 64.f));
    const float fr = pos * inv;
    float sn, cs;
    __sincosf(fr, &sn, &cs);
    const float xe = bf2f(e[2 * q]);
    const float xo = bf2f(e[2 * q + 1]);
    e[2 * q]     = f2bf(xe * cs - xo * sn);
    e[2 * q + 1] = f2bf(xo * cs + xe * sn);
  }
  *(uint4*)p = v;
}

// ---------------- V transpose: V[m, n] (stride ldv) -> Vt[b*1024 + n][m % 2048] ----------------
__global__ void transpose_v(const unsigned short* __restrict__ V, int ldv,
                            unsigned short* __restrict__ Vt) {
  __shared__ unsigned short tile[32][40];
  const int t = threadIdx.x;
  const int n0 = blockIdx.x * 32;   // V col (0..1023)
  const int m0 = blockIdx.y * 32;   // V row (0..4095)
  const int r = t >> 3;
  const int c = (t & 7) << 2;
  const unsigned short* src = V + (size_t)(m0 + r) * ldv + n0 + c;
  ushort4 d = *(const ushort4*)src;
  tile[r][c] = d.x; tile[r][c + 1] = d.y; tile[r][c + 2] = d.z; tile[r][c + 3] = d.w;
  __syncthreads();
  const int b = m0 >> 11;
  unsigned short* dst = Vt + (size_t)(b * 1024 + n0 + r) * 2048 + (m0 & 2047) + c;
  ushort4 o;
  o.x = tile[c][r]; o.y = tile[c + 1][r]; o.z = tile[c + 2][r]; o.w = tile[c + 3][r];
  *(ushort4*)dst = o;
}

// ---------------- causal GQA flash attention ----------------
// grid (S/128, B*NH); block 256 = 4 waves; each wave owns 32 q-rows.
__global__ __launch_bounds__(256, 2)
void attn_kernel(const unsigned short* __restrict__ Q,   // ld = ldqk
                 const unsigned short* __restrict__ Km,  // ld = ldqk
                 const unsigned short* __restrict__ Vt,  // [2048][2048]
                 unsigned short* __restrict__ O,         // [4096][4096]
                 int ldqk) {
  __shared__ unsigned short sK[32][128];
  __shared__ unsigned short sVt[128][32];
  __shared__ unsigned short sP[4][32][32];

  const int t = threadIdx.x;
  const int wave = t >> 6, lane = t & 63;
  const int row16 = lane & 15, kgrp = lane >> 4;
  const int qt = blockIdx.x;
  const int bh = blockIdx.y;
  const int b = bh >> 5, h = bh & 31;
  const int kh = h >> 2;                 // n_rep = 4 (repeat_interleave)
  const int q0 = qt * 128;
  const int wq = wave * 32;

  // Q fragments, hoisted (reused across all KV tiles)
  bf16x8 qf[2][4];
  const unsigned short* qbase = Q + (size_t)(b * S_LEN + q0 + wq) * ldqk + h * HDIM;
#pragma unroll
  for (int fi = 0; fi < 2; fi++)
#pragma unroll
    for (int kd = 0; kd < 4; kd++)
      qf[fi][kd] = *(const bf16x8*)&qbase[(size_t)(fi * 16 + row16) * ldqk + kd * 32 + kgrp * 8];

  f32x4 acc[2][8];
#pragma unroll
  for (int fi = 0; fi < 2; fi++)
#pragma unroll
    for (int nj = 0; nj < 8; nj++) acc[fi][nj] = (f32x4){0.f, 0.f, 0.f, 0.f};
  float mrow[2][4], lrow[2][4];
#pragma unroll
  for (int fi = 0; fi < 2; fi++)
#pragma unroll
    for (int jj = 0; jj < 4; jj++) { mrow[fi][jj] = -1e30f; lrow[fi][jj] = 0.f; }

  const int ntiles = qt * 4 + 4;
  const int krow = t >> 4, kcol = (t & 15) << 3;   // K tile [32][128]
  const int vrow = t >> 2, vcol = (t & 3) << 3;    // Vt tile [128][32]
  const unsigned short* Kp = Km + (size_t)(b * S_LEN) * ldqk + kh * HDIM;
  const unsigned short* Vp = Vt + (size_t)((b * NKVH + kh) * HDIM) * 2048;

  for (int it = 0; it < ntiles; ++it) {
    const int kv0 = it * 32;
    gload16(Kp + (size_t)(kv0 + krow) * ldqk + kcol,      &sK[krow][kcol]);
    gload16(Kp + (size_t)(kv0 + krow + 16) * ldqk + kcol, &sK[krow + 16][kcol]);
    gload16(Vp + (size_t)vrow * 2048 + kv0 + vcol,        &sVt[vrow][vcol]);
    gload16(Vp + (size_t)(vrow + 64) * 2048 + kv0 + vcol, &sVt[vrow + 64][vcol]);
    asm volatile("s_waitcnt vmcnt(0)" ::: "memory");
    __syncthreads();

    // QK^T: S[32 q][32 kv]
    f32x4 sf[2][2];
#pragma unroll
    for (int fi = 0; fi < 2; fi++)
#pragma unroll
      for (int cj = 0; cj < 2; cj++) sf[fi][cj] = (f32x4){0.f, 0.f, 0.f, 0.f};
#pragma unroll
    for (int cj = 0; cj < 2; cj++)
#pragma unroll
      for (int kd = 0; kd < 4; kd++) {
        bf16x8 kf = *(const bf16x8*)&sK[cj * 16 + row16][kd * 32 + kgrp * 8];
        sf[0][cj] = __builtin_amdgcn_mfma_f32_16x16x32_bf16(qf[0][kd], kf, sf[0][cj], 0, 0, 0);
        sf[1][cj] = __builtin_amdgcn_mfma_f32_16x16x32_bf16(qf[1][kd], kf, sf[1][cj], 0, 0, 0);
      }

    // mask + online softmax (fp32)
#pragma unroll
    for (int fi = 0; fi < 2; fi++) {
#pragma unroll
      for (int jj = 0; jj < 4; jj++) {
        const int qrow = q0 + wq + fi * 16 + kgrp * 4 + jj;
        float s0 = sf[fi][0][jj] * SCALE;
        float s1 = sf[fi][1][jj] * SCALE;
        if (kv0 + row16 > qrow)      s0 = -1e30f;
        if (kv0 + 16 + row16 > qrow) s1 = -1e30f;
        float mx = fmaxf(s0, s1);
        mx = fmaxf(mx, __shfl_xor(mx, 1));
        mx = fmaxf(mx, __shfl_xor(mx, 2));
        mx = fmaxf(mx, __shfl_xor(mx, 4));
        mx = fmaxf(mx, __shfl_xor(mx, 8));
        const float mold = mrow[fi][jj];
        const float mnew = fmaxf(mold, mx);
        const float corr = __expf(mold - mnew);
        const float p0 = __expf(s0 - mnew);
        const float p1 = __expf(s1 - mnew);
        float ps = p0 + p1;
        ps += __shfl_xor(ps, 1);
        ps += __shfl_xor(ps, 2);
        ps += __shfl_xor(ps, 4);
        ps += __shfl_xor(ps, 8);
        lrow[fi][jj] = lrow[fi][jj] * corr + ps;
        mrow[fi][jj] = mnew;
#pragma unroll
        for (int nj = 0; nj < 8; nj++) acc[fi][nj][jj] *= corr;
        sP[wave][fi * 16 + kgrp * 4 + jj][row16]      = f2bf(p0);
        sP[wave][fi * 16 + kgrp * 4 + jj][16 + row16] = f2bf(p1);
      }
    }
    asm volatile("s_waitcnt lgkmcnt(0)" ::: "memory");  // wave-internal sP write->read

    // PV: acc[32 q][128 d] += P[32][32] @ V[32][128]
    bf16x8 pa0 = *(const bf16x8*)&sP[wave][row16][kgrp * 8];
    bf16x8 pa1 = *(const bf16x8*)&sP[wave][16 + row16][kgrp * 8];
#pragma unroll
    for (int nj = 0; nj < 8; nj++) {
      bf16x8 vb = *(const bf16x8*)&sVt[nj * 16 + row16][kgrp * 8];
      acc[0][nj] = __builtin_amdgcn_mfma_f32_16x16x32_bf16(pa0, vb, acc[0][nj], 0, 0, 0);
      acc[1][nj] = __builtin_amdgcn_mfma_f32_16x16x32_bf16(pa1, vb, acc[1][nj], 0, 0, 0);
    }
    __syncthreads();
  }

  // epilogue: normalize, write bf16
#pragma unroll
  for (int fi = 0; fi < 2; fi++) {
#pragma unroll
    for (int jj = 0; jj < 4; jj++) {
      const float inv_l = 1.0f / lrow[fi][jj];
      const size_t orow = (size_t)(b * S_LEN + q0 + wq + fi * 16 + kgrp * 4 + jj) * 4096 + h * HDIM;
#pragma unroll
      for (int nj = 0; nj < 8; nj++)
        O[orow + nj * 16 + row16] = f2bf(acc[fi][nj][jj] * inv_l);
    }
  }
}

// ---------------- launch ----------------
extern "C" void kernel_launch(void* const* d_in, const int* in_sizes, int n_in,
                              void* d_out, int out_size, void* d_ws, size_t ws_size,
                              hipStream_t stream) {
  const float* hs = (const float*)d_in[0];
  const int*  pos = (const int*)d_in[1];
  const float* Wq = (const float*)d_in[2];
  const float* bq = (const float*)d_in[3];
  const float* Wk = (const float*)d_in[4];
  const float* bk = (const float*)d_in[5];
  const float* Wv = (const float*)d_in[6];
  const float* bv = (const float*)d_in[7];
  const float* Wo = (const float*)d_in[8];
  const float* bo = (const float*)d_in[9];
  float* out = (float*)d_out;

  char* ws = (char*)d_ws;
  unsigned short* hbf  = (unsigned short*)(ws);               // 33.5 MB; later attn_out
  unsigned short* Wbuf = (unsigned short*)(ws + 33554432);    // 50.3 MB (Wqkv; later Wo)
  unsigned short* QKV  = (unsigned short*)(ws + 83886080);    // 50.3 MB [4096][6144]
  unsigned short* Vtb  = (unsigned short*)(ws + 134217728);   // 8.4 MB  [2048][2048]
  float*          biasb= (float*)(ws + 142606336);            // 6144 floats

  // 1. casts (hidden + fused QKV weights, contiguous)
  cast_f32_bf16<<<2048, 256, 0, stream>>>((const float4*)hs, (ushort4*)hbf, 4194304);
  cast_f32_bf16<<<2048, 256, 0, stream>>>((const float4*)Wq, (ushort4*)Wbuf, 4194304);
  cast_f32_bf16<<<1024, 256, 0, stream>>>((const float4*)Wk, (ushort4*)(Wbuf + 16777216), 1048576);
  cast_f32_bf16<<<1024, 256, 0, stream>>>((const float4*)Wv, (ushort4*)(Wbuf + 20971520), 1048576);
  hipMemcpyAsync(biasb, bq, 4096 * 4, hipMemcpyDeviceToDevice, stream);
  hipMemcpyAsync(biasb + 4096, bk, 1024 * 4, hipMemcpyDeviceToDevice, stream);
  hipMemcpyAsync(biasb + 5120, bv, 1024 * 4, hipMemcpyDeviceToDevice, stream);

  // 2. fused QKV projection: [4096,6144]
  gemm_bt<0><<<dim3(48, 32), 256, 0, stream>>>(hbf, Wbuf, biasb, QKV, MROWS, LDQKV, 4096);

  // 3. Wo cast into Wbuf (Wqkv no longer needed)
  cast_f32_bf16<<<2048, 256, 0, stream>>>((const float4*)Wo, (ushort4*)Wbuf, 4194304);

  // 4. RoPE on Q (cols 0..4095) and K (cols 4096..5119)
  rope_kernel<<<8192, 256, 0, stream>>>(QKV, pos, 4096, LDQKV);
  rope_kernel<<<2048, 256, 0, stream>>>(QKV + 4096, pos, 1024, LDQKV);

  // 5. V transpose (cols 5120..6143) -> Vt[2048][2048]
  transpose_v<<<dim3(32, 128), 256, 0, stream>>>(QKV + 5120, LDQKV, Vtb);

  // 6. causal GQA flash attention -> hbf (hidden no longer needed)
  attn_kernel<<<dim3(16, 64), 256, 0, stream>>>(QKV, QKV + 4096, Vtb, hbf, LDQKV);

  // 7. output projection -> fp32 d_out
  gemm_bt<1><<<dim3(32, 32), 256, 0, stream>>>(hbf, Wbuf, bo, out, MROWS, 4096, 4096);
}

// Round 3
// 674.550 us; speedup vs baseline: 1.4215x; 1.4215x over previous
//
#include <hip/hip_runtime.h>
#include <stdint.h>

typedef __bf16 bf16x8 __attribute__((ext_vector_type(8)));
typedef float f32x4 __attribute__((ext_vector_type(4)));
typedef float f32x16 __attribute__((ext_vector_type(16)));

#define S_LEN 2048
#define NKVH 8
#define HDIM 128
#define MROWS 4096        // B*S
#define LDQKV 6144        // fused QKV row stride
#define SCALE 0.08838834764831845f
#define C_LOG2 0.1275405707067851f   // SCALE * log2(e)
#define THR_RAW 62.7f                // 8 / C_LOG2

__device__ __forceinline__ unsigned short f2bf(float f) {
  unsigned u = __float_as_uint(f);
  u += 0x7FFFu + ((u >> 16) & 1u);
  return (unsigned short)(u >> 16);
}
__device__ __forceinline__ float bf2f(unsigned short h) {
  return __uint_as_float(((unsigned)h) << 16);
}

__device__ __forceinline__ void gload16(const unsigned short* g, unsigned short* l) {
  __builtin_amdgcn_global_load_lds(
      (__attribute__((address_space(1))) void*)(g),
      (__attribute__((address_space(3))) void*)(l), 16, 0, 0);
}

// ---------------- fp32 -> bf16 cast, vectorized ----------------
__global__ void cast_f32_bf16(const float4* __restrict__ in, ushort4* __restrict__ out, int n4) {
  int i = blockIdx.x * 256 + threadIdx.x;
  const int stride = gridDim.x * 256;
  for (; i < n4; i += stride) {
    float4 v = in[i];
    ushort4 o;
    o.x = f2bf(v.x); o.y = f2bf(v.y); o.z = f2bf(v.z); o.w = f2bf(v.w);
    out[i] = o;
  }
}

// ---------------- GEMM: C[M,N] = A[M,K] @ Bw[N,K]^T + bias ----------------
template <int OUTF>
__global__ __launch_bounds__(256, 2)
void gemm_bt(const unsigned short* __restrict__ A,
             const unsigned short* __restrict__ Bw,
             const float* __restrict__ bias,
             void* __restrict__ C,
             int M, int N, int K) {
  __shared__ unsigned short sA[128][32];
  __shared__ unsigned short sB[128][32];

  const int t = threadIdx.x;
  const int lane = t & 63;
  const int wave = t >> 6;
  const int wr = wave >> 1, wc = wave & 1;
  const int row16 = lane & 15, kgrp = lane >> 4;
  const int m0 = blockIdx.y * 128;
  const int n0 = blockIdx.x * 128;

  const int srow = t >> 2;
  const int scol = (t & 3) << 3;

  const unsigned short* Ap = A + (size_t)(m0 + srow) * K + scol;
  const unsigned short* Bp = Bw + (size_t)(n0 + srow) * K + scol;
  unsigned short* sAp = &sA[srow][scol];
  unsigned short* sBp = &sB[srow][scol];

  f32x4 acc[4][4];
#pragma unroll
  for (int i = 0; i < 4; i++)
#pragma unroll
    for (int j = 0; j < 4; j++) acc[i][j] = (f32x4){0.f, 0.f, 0.f, 0.f};

  for (int k0 = 0; k0 < K; k0 += 32) {
    gload16(Ap, sAp);
    gload16(Ap + (size_t)64 * K, sAp + 64 * 32);
    gload16(Bp, sBp);
    gload16(Bp + (size_t)64 * K, sBp + 64 * 32);
    Ap += 32; Bp += 32;
    asm volatile("s_waitcnt vmcnt(0)" ::: "memory");
    __syncthreads();

    bf16x8 af[4], bfr[4];
#pragma unroll
    for (int i = 0; i < 4; i++) af[i] = *(const bf16x8*)&sA[wr * 64 + i * 16 + row16][kgrp * 8];
#pragma unroll
    for (int j = 0; j < 4; j++) bfr[j] = *(const bf16x8*)&sB[wc * 64 + j * 16 + row16][kgrp * 8];
#pragma unroll
    for (int i = 0; i < 4; i++)
#pragma unroll
      for (int j = 0; j < 4; j++)
        acc[i][j] = __builtin_amdgcn_mfma_f32_16x16x32_bf16(af[i], bfr[j], acc[i][j], 0, 0, 0);
    __syncthreads();
  }

#pragma unroll
  for (int i = 0; i < 4; i++) {
#pragma unroll
    for (int j = 0; j < 4; j++) {
      const int gr = m0 + wr * 64 + i * 16 + kgrp * 4;
      const int gc = n0 + wc * 64 + j * 16 + row16;
      const float bv = bias[gc];
#pragma unroll
      for (int jj = 0; jj < 4; jj++) {
        float v = acc[i][j][jj] + bv;
        if (OUTF) ((float*)C)[(size_t)(gr + jj) * N + gc] = v;
        else ((unsigned short*)C)[(size_t)(gr + jj) * N + gc] = f2bf(v);
      }
    }
  }
}

// ---------------- RoPE (interleaved), in-place on bf16, row stride ld ----------------
__global__ void rope_kernel(unsigned short* __restrict__ X,
                            const int* __restrict__ pos_ids,
                            int ncols, int ld) {
  const int perrow = ncols >> 3;
  int idx = blockIdx.x * 256 + threadIdx.x;
  const int row = idx / perrow;
  const int c0 = (idx - row * perrow) << 3;
  const float pos = (float)pos_ids[row];
  unsigned short* p = X + (size_t)row * ld + c0;
  uint4 v = *(uint4*)p;
  unsigned short* e = (unsigned short*)&v;
  const int p0 = (c0 & 127) >> 1;
#pragma unroll
  for (int q = 0; q < 4; ++q) {
    const float inv = exp2f(-(float)(p0 + q) * (19.931568569324174f / 64.f));
    const float fr = pos * inv;
    float sn, cs;
    __sincosf(fr, &sn, &cs);
    const float xe = bf2f(e[2 * q]);
    const float xo = bf2f(e[2 * q + 1]);
    e[2 * q]     = f2bf(xe * cs - xo * sn);
    e[2 * q + 1] = f2bf(xo * cs + xe * sn);
  }
  *(uint4*)p = v;
}

// ---------------- V transpose: V[m, n] (stride ldv) -> Vt[b*1024 + n][m % 2048] ----------------
__global__ void transpose_v(const unsigned short* __restrict__ V, int ldv,
                            unsigned short* __restrict__ Vt) {
  __shared__ unsigned short tile[32][40];
  const int t = threadIdx.x;
  const int n0 = blockIdx.x * 32;   // V col (0..1023)
  const int m0 = blockIdx.y * 32;   // V row (0..4095)
  const int r = t >> 3;
  const int c = (t & 7) << 2;
  const unsigned short* src = V + (size_t)(m0 + r) * ldv + n0 + c;
  ushort4 d = *(const ushort4*)src;
  tile[r][c] = d.x; tile[r][c + 1] = d.y; tile[r][c + 2] = d.z; tile[r][c + 3] = d.w;
  __syncthreads();
  const int b = m0 >> 11;
  unsigned short* dst = Vt + (size_t)(b * 1024 + n0 + r) * 2048 + (m0 & 2047) + c;
  ushort4 o;
  o.x = tile[c][r]; o.y = tile[c + 1][r]; o.z = tile[c + 2][r]; o.w = tile[c + 3][r];
  *(ushort4*)dst = o;
}

// ---------------- causal GQA flash attention, m214-style 8-wave 32x32 ----------------
// grid (8, B*NH); block 512 = 8 waves; each wave owns 32 q rows.
// Swapped QK^T (mfma(K,Q)) -> lane-local softmax; cross-half ops via shfl_xor(,32)
// (round-2 permlane asm had a same-register-collapse bug -> lsum=0 -> NaN).
__global__ __launch_bounds__(512, 2)
void attn_kernel2(const unsigned short* __restrict__ QKV,
                  const unsigned short* __restrict__ Vt,
                  unsigned short* __restrict__ O) {
  __shared__ unsigned short sK[2][64 * 128];
  __shared__ unsigned short sV[2][128 * 64];

  const int t = threadIdx.x;
  const int lane = t & 63;
  const int w = t >> 6;
  const int l31 = lane & 31;
  const int hi = lane >> 5;
  const int qt = 7 - blockIdx.x;          // heavy tiles dispatch first
  const int bh = blockIdx.y;
  const int b = bh >> 5, h = bh & 31;
  const int kh = h >> 2;                  // n_rep = 4 (repeat_interleave)
  const int q0 = qt * 256;
  const int qw = q0 + w * 32;
  const int qg = qw + l31;                // this lane's q row (softmax state owner)

  const int ntiles = (q0 + 256) >> 6;     // 4qt+4
  const int myTiles = (qw + 95) >> 6;     // ceil((qw+32)/64)

  // ---- staging geometry (pre-swizzled global source, linear LDS dest) ----
  const int krow0 = t >> 4;               // 0..31 (pass2: +32)
  const int kslot = t & 15;
  const int vrow0 = t >> 3;               // 0..63 (pass2: +64)
  const int vslot = t & 7;
  const unsigned short* Kp = QKV + (size_t)(b * S_LEN) * LDQKV + 4096 + kh * HDIM;
  const unsigned short* Vp = Vt + (size_t)(b * 1024 + kh * HDIM) * 2048;
  const int ksw = (kslot ^ (krow0 & 7)) << 3;
  const int vsw = (vslot ^ (vrow0 & 7)) << 3;
  const unsigned short* KpA = Kp + (size_t)krow0 * LDQKV + ksw;
  const unsigned short* KpB = Kp + (size_t)(krow0 + 32) * LDQKV + ksw;
  const unsigned short* VpA = Vp + (size_t)vrow0 * 2048 + vsw;
  const unsigned short* VpB = Vp + (size_t)(vrow0 + 64) * 2048 + vsw;

#define STAGE(bufi, kv0m)                                              \
  {                                                                    \
    gload16(KpA + (size_t)(kv0m)*LDQKV, &sK[bufi][t * 8]);             \
    gload16(KpB + (size_t)(kv0m)*LDQKV, &sK[bufi][4096 + t * 8]);      \
    gload16(VpA + (kv0m), &sV[bufi][t * 8]);                           \
    gload16(VpB + (kv0m), &sV[bufi][4096 + t * 8]);                    \
  }

  // ---- Q fragments (hoisted; B-operand of swapped QK^T) ----
  bf16x8 qf[8];
  {
    const unsigned short* qb = QKV + (size_t)(b * S_LEN + qw + l31) * LDQKV + h * HDIM + hi * 8;
#pragma unroll
    for (int kd = 0; kd < 8; kd++) qf[kd] = *(const bf16x8*)(qb + kd * 16);
  }

  f32x16 o[4];
#pragma unroll
  for (int nt = 0; nt < 4; nt++)
#pragma unroll
    for (int r = 0; r < 16; r++) o[nt][r] = 0.f;
  float m = -1e30f, lsum = 0.f;

  const int rw7 = (l31 & 7) << 4;          // byte-swizzle field for LDS reads
  const int kswz = (hi << 4) ^ rw7;        // combines hi-halfword select with row swizzle
  const int kbase0 = l31 * 128;            // ushort offsets (row stride 128 us = 256B)
  const int vbase = l31 * 64;              // sV row stride 64 us = 128B

  STAGE(0, 0);
  int buf = 0;
  for (int it = 0; it < ntiles; ++it) {
    if (it + 1 < ntiles) {
      STAGE(buf ^ 1, (it + 1) << 6);
      asm volatile("s_waitcnt vmcnt(4)" ::: "memory");
    } else {
      asm volatile("s_waitcnt vmcnt(0)" ::: "memory");
    }
    __builtin_amdgcn_s_barrier();

    if (it < myTiles) {
      const unsigned short* sKc = &sK[buf][0];
      const unsigned short* sVc = &sV[buf][0];
      const int kv0 = it << 6;

      // ---- QK^T (swapped): st[s][r] = S[q=qg][kv = kv0+32s+crow(r,hi)] ----
      f32x16 st[2];
#pragma unroll
      for (int r = 0; r < 16; r++) { st[0][r] = 0.f; st[1][r] = 0.f; }
      __builtin_amdgcn_s_setprio(1);
#pragma unroll
      for (int kd = 0; kd < 8; kd++) {
        bf16x8 k0 = *(const bf16x8*)(sKc + kbase0 + (((kd << 5) ^ kswz) >> 1));
        bf16x8 k1 = *(const bf16x8*)(sKc + 4096 + kbase0 + (((kd << 5) ^ kswz) >> 1));
        st[0] = __builtin_amdgcn_mfma_f32_32x32x16_bf16(k0, qf[kd], st[0], 0, 0, 0);
        st[1] = __builtin_amdgcn_mfma_f32_32x32x16_bf16(k1, qf[kd], st[1], 0, 0, 0);
      }
      __builtin_amdgcn_s_setprio(0);

      // ---- causal mask (diagonal tile only) ----
      if (it == myTiles - 1) {
#pragma unroll
        for (int s2 = 0; s2 < 2; s2++)
#pragma unroll
          for (int r = 0; r < 16; r++) {
            const int kvg = kv0 + s2 * 32 + (r & 3) + 8 * (r >> 2) + 4 * hi;
            if (kvg > qg) st[s2][r] = -1e30f;
          }
      }

      // ---- tile max (lane-local + cross-half shfl) ----
      float tmax = st[0][0];
#pragma unroll
      for (int r = 1; r < 16; r++) tmax = fmaxf(tmax, st[0][r]);
#pragma unroll
      for (int r = 0; r < 16; r++) tmax = fmaxf(tmax, st[1][r]);
      tmax = fmaxf(tmax, __shfl_xor(tmax, 32));

      // ---- defer-max rescale (T13) ----
      if (!__all(tmax <= m + THR_RAW)) {
        const float mnew = fmaxf(m, tmax);
        const float corr = exp2f((m - mnew) * C_LOG2);
        lsum *= corr;
#pragma unroll
        for (int r = 0; r < 16; r++) {
          const int src = (r & 3) + 8 * (r >> 2) + 4 * hi;
          const float cr = __shfl(corr, src);
#pragma unroll
          for (int nt = 0; nt < 4; nt++) o[nt][r] *= cr;
        }
        m = mnew;
      }
      const float mC = m * C_LOG2;

      // ---- exp + row sum (cross-half shfl) ----
#pragma unroll
      for (int s2 = 0; s2 < 2; s2++)
#pragma unroll
        for (int r = 0; r < 16; r++) st[s2][r] = exp2f(fmaf(st[s2][r], C_LOG2, -mC));
      float tsum = st[0][0];
#pragma unroll
      for (int r = 1; r < 16; r++) tsum += st[0][r];
#pragma unroll
      for (int r = 0; r < 16; r++) tsum += st[1][r];
      tsum += __shfl_xor(tsum, 32);
      lsum += tsum;

      // ---- P -> bf16 A-fragments (cvt_pk + cross-half shfl_xor redistribution) ----
      // target pa[2s2+c] word w on lane: hi=0: {pw0,pw1, partner pw0, partner pw1}
      //                                  hi=1: {partner pw2, partner pw3, pw2, pw3}
      bf16x8 pa[4];
#pragma unroll
      for (int s2 = 0; s2 < 2; s2++) {
        unsigned pw[8];
#pragma unroll
        for (int i = 0; i < 8; i++)
          asm("v_cvt_pk_bf16_f32 %0, %1, %2" : "=v"(pw[i]) : "v"(st[s2][2 * i]), "v"(st[s2][2 * i + 1]));
        const unsigned x0 = (unsigned)__shfl_xor((int)pw[0], 32);
        const unsigned x1 = (unsigned)__shfl_xor((int)pw[1], 32);
        const unsigned x2 = (unsigned)__shfl_xor((int)pw[2], 32);
        const unsigned x3 = (unsigned)__shfl_xor((int)pw[3], 32);
        const unsigned x4 = (unsigned)__shfl_xor((int)pw[4], 32);
        const unsigned x5 = (unsigned)__shfl_xor((int)pw[5], 32);
        const unsigned x6 = (unsigned)__shfl_xor((int)pw[6], 32);
        const unsigned x7 = (unsigned)__shfl_xor((int)pw[7], 32);
        union { unsigned u[4]; bf16x8 v; } u0, u1;
        u0.u[0] = hi ? x2 : pw[0];
        u0.u[1] = hi ? x3 : pw[1];
        u0.u[2] = hi ? pw[2] : x0;
        u0.u[3] = hi ? pw[3] : x1;
        u1.u[0] = hi ? x6 : pw[4];
        u1.u[1] = hi ? x7 : pw[5];
        u1.u[2] = hi ? pw[6] : x4;
        u1.u[3] = hi ? pw[7] : x5;
        pa[2 * s2] = u0.v; pa[2 * s2 + 1] = u1.v;
      }

      // ---- PV: o[nt] += P @ V ----
      __builtin_amdgcn_s_setprio(1);
#pragma unroll
      for (int nt = 0; nt < 4; nt++) {
        const unsigned short* vr = sVc + vbase + nt * 2048;  // (nt*32 rows)*64
#pragma unroll
        for (int ks = 0; ks < 4; ks++) {
          bf16x8 vb = *(const bf16x8*)(vr + (((ks << 5) ^ kswz) >> 1));
          o[nt] = __builtin_amdgcn_mfma_f32_32x32x16_bf16(pa[ks], vb, o[nt], 0, 0, 0);
        }
      }
      __builtin_amdgcn_s_setprio(0);
    }

    asm volatile("" ::: "memory");
    __builtin_amdgcn_s_barrier();
    buf ^= 1;
  }

  // ---- epilogue: normalize (cross-lane linv via shfl), write bf16 ----
  const float linv = 1.0f / lsum;
#pragma unroll
  for (int r = 0; r < 16; r++) {
    const int qr = (r & 3) + 8 * (r >> 2) + 4 * hi;
    const float lr = __shfl(linv, qr);
    unsigned short* orow = O + (size_t)(b * S_LEN + qw + qr) * 4096 + h * HDIM + l31;
#pragma unroll
    for (int nt = 0; nt < 4; nt++) orow[nt * 32] = f2bf(o[nt][r] * lr);
  }
#undef STAGE
}

// ---------------- launch ----------------
extern "C" void kernel_launch(void* const* d_in, const int* in_sizes, int n_in,
                              void* d_out, int out_size, void* d_ws, size_t ws_size,
                              hipStream_t stream) {
  const float* hs = (const float*)d_in[0];
  const int*  pos = (const int*)d_in[1];
  const float* Wq = (const float*)d_in[2];
  const float* bq = (const float*)d_in[3];
  const float* Wk = (const float*)d_in[4];
  const float* bk = (const float*)d_in[5];
  const float* Wv = (const float*)d_in[6];
  const float* bv = (const float*)d_in[7];
  const float* Wo = (const float*)d_in[8];
  const float* bo = (const float*)d_in[9];
  float* out = (float*)d_out;

  char* ws = (char*)d_ws;
  unsigned short* hbf  = (unsigned short*)(ws);               // hidden bf16; later attn_out
  unsigned short* Wbuf = (unsigned short*)(ws + 33554432);    // Wqkv bf16; later Wo
  unsigned short* QKV  = (unsigned short*)(ws + 83886080);    // [4096][6144]
  unsigned short* Vtb  = (unsigned short*)(ws + 134217728);   // [2048][2048]
  float*          biasb= (float*)(ws + 142606336);            // 6144 floats

  // 1. casts (hidden + fused QKV weights, contiguous)
  cast_f32_bf16<<<2048, 256, 0, stream>>>((const float4*)hs, (ushort4*)hbf, 4194304);
  cast_f32_bf16<<<2048, 256, 0, stream>>>((const float4*)Wq, (ushort4*)Wbuf, 4194304);
  cast_f32_bf16<<<1024, 256, 0, stream>>>((const float4*)Wk, (ushort4*)(Wbuf + 16777216), 1048576);
  cast_f32_bf16<<<1024, 256, 0, stream>>>((const float4*)Wv, (ushort4*)(Wbuf + 20971520), 1048576);
  hipMemcpyAsync(biasb, bq, 4096 * 4, hipMemcpyDeviceToDevice, stream);
  hipMemcpyAsync(biasb + 4096, bk, 1024 * 4, hipMemcpyDeviceToDevice, stream);
  hipMemcpyAsync(biasb + 5120, bv, 1024 * 4, hipMemcpyDeviceToDevice, stream);

  // 2. fused QKV projection: [4096,6144]
  gemm_bt<0><<<dim3(48, 32), 256, 0, stream>>>(hbf, Wbuf, biasb, QKV, MROWS, LDQKV, 4096);

  // 3. Wo cast into Wbuf (Wqkv no longer needed)
  cast_f32_bf16<<<2048, 256, 0, stream>>>((const float4*)Wo, (ushort4*)Wbuf, 4194304);

  // 4. RoPE on Q (cols 0..4095) and K (cols 4096..5119)
  rope_kernel<<<8192, 256, 0, stream>>>(QKV, pos, 4096, LDQKV);
  rope_kernel<<<2048, 256, 0, stream>>>(QKV + 4096, pos, 1024, LDQKV);

  // 5. V transpose (cols 5120..6143) -> Vt[2048][2048]
  transpose_v<<<dim3(32, 128), 256, 0, stream>>>(QKV + 5120, LDQKV, Vtb);

  // 6. causal GQA flash attention (8-wave 32x32, swapped-QK^T) -> hbf
  attn_kernel2<<<dim3(8, 64), 512, 0, stream>>>(QKV, Vtb, hbf);

  // 7. output projection -> fp32 d_out
  gemm_bt<1><<<dim3(32, 32), 256, 0, stream>>>(hbf, Wbuf, bo, out, MROWS, 4096, 4096);
}

// Round 5
// 613.917 us; speedup vs baseline: 1.5619x; 1.0988x over previous
//
#include <hip/hip_runtime.h>
#include <stdint.h>

typedef __bf16 bf16x8 __attribute__((ext_vector_type(8)));
typedef float f32x4 __attribute__((ext_vector_type(4)));
typedef float f32x16 __attribute__((ext_vector_type(16)));

#define S_LEN 2048
#define NKVH 8
#define HDIM 128
#define MROWS 4096        // B*S
#define LDQKV 6144        // fused QKV row stride
#define SCALE 0.08838834764831845f
#define C_LOG2 0.1275405707067851f   // SCALE * log2(e)
#define THR_RAW 62.7f                // 8 / C_LOG2

__device__ __forceinline__ unsigned short f2bf(float f) {
  unsigned u = __float_as_uint(f);
  u += 0x7FFFu + ((u >> 16) & 1u);
  return (unsigned short)(u >> 16);
}
__device__ __forceinline__ float bf2f(unsigned short h) {
  return __uint_as_float(((unsigned)h) << 16);
}

__device__ __forceinline__ void gload16(const unsigned short* g, unsigned short* l) {
  __builtin_amdgcn_global_load_lds(
      (__attribute__((address_space(1))) void*)(g),
      (__attribute__((address_space(3))) void*)(l), 16, 0, 0);
}

// ---------------- fp32 -> bf16 cast, vectorized ----------------
__global__ void cast_f32_bf16(const float4* __restrict__ in, ushort4* __restrict__ out, int n4) {
  int i = blockIdx.x * 256 + threadIdx.x;
  const int stride = gridDim.x * 256;
  for (; i < n4; i += stride) {
    float4 v = in[i];
    ushort4 o;
    o.x = f2bf(v.x); o.y = f2bf(v.y); o.z = f2bf(v.z); o.w = f2bf(v.w);
    out[i] = o;
  }
}

// ---------------- GEMM 256x256, BK=64, 8 waves, 4-phase counted-vmcnt pipeline ----
// C[M,N] = A[M,K] @ Bw[N,K]^T + bias.
// LDS: [2 buf][4 units of 16KB]: u0=A rows {0-63,128-191}, u1=B rows qn0,
//      u2=B rows qn1, u3=A rows {64-127,192-255}. T2 swizzle: slot ^= row&7
//      (pre-swizzled global source + same XOR on ds_read; rule 21).
// Tile T computed from buf[T&1]; tile T+1 staged into buf[~T&1] across T's
// 4 phases in first-use order. Every phase: vmcnt+s_barrier handoff.
// Steady state: 3 units (6 loads) in flight; vmcnt(4) drains exactly the 2
// loads the phase reads. LAST tile stages nothing, so the counts peel to
// vmcnt(2)@phase1 / vmcnt(0)@phase2 (round-4 bug: vmcnt(4) was a no-op there
// and phases 1/2 raced the in-flight u2/u3 loads).
template <int OUTF>
__global__ __launch_bounds__(512, 2)
void gemm256(const unsigned short* __restrict__ A,
             const unsigned short* __restrict__ Bw,
             const float* __restrict__ bias,
             void* __restrict__ C,
             int M, int N, int K) {
  __shared__ unsigned short lds[2][4][8192];   // 128 KiB

  const int t = threadIdx.x;
  const int lane = t & 63;
  const int w = t >> 6;
  const int wr = w >> 2, wc = w & 3;           // 2 x 4 waves
  const int row16 = lane & 15, kgrp = lane >> 4;
  const int m0 = blockIdx.y * 256, n0 = blockIdx.x * 256;

  // ---- staging geometry (load0: chunk t, load1: chunk 512+t) ----
  const int riu = t >> 3;                           // 0..63
  const int col = (((t & 7) ^ (riu & 7)) << 3);     // pre-swizzled src col
  const int rB0 = (riu & 31) + ((riu >> 5) << 6);   // B qn0 row for load0
  const unsigned short* pA = A + (size_t)(m0 + riu) * K + col;   // A qm0 load0
  const unsigned short* pB = Bw + (size_t)(n0 + rB0) * K + col;  // load1 rows = +128

#define STG(nb_, u_, src_)                                                  \
  {                                                                         \
    gload16((src_), &lds[nb_][u_][t * 8]);                                  \
    gload16((src_) + (size_t)128 * K, &lds[nb_][u_][4096 + t * 8]);         \
  }

  // ---- read geometry ----
  const int sw = row16 & 7;
  const int abase = (wr * 64 + row16) * 64;   // ushort offset within A unit
  const int bbase = (wc * 32 + row16) * 64;   // within B unit

  f32x4 acc[8][4];
#pragma unroll
  for (int i = 0; i < 8; i++)
#pragma unroll
    for (int j = 0; j < 4; j++) acc[i][j] = (f32x4){0.f, 0.f, 0.f, 0.f};

  bf16x8 afr[4][2], bfr[2][2][2];
  const int NT = K >> 6;

  // prologue: tile 0 -> buf 0 (8 loads)
  STG(0, 0, pA);
  STG(0, 1, pB);
  STG(0, 2, pB + (size_t)32 * K);
  STG(0, 3, pA + (size_t)64 * K);

  for (int T = 0; T < NT; ++T) {
    const int cb = T & 1, nb = cb ^ 1;
    const unsigned short* Lc = &lds[cb][0][0];
    const size_t kk = (size_t)(T + 1) << 6;
    const bool st = (T + 1 < NT);

    // ---------- phase 0: quadrant (qm0, qn0) ----------
    asm volatile("s_waitcnt vmcnt(4)\n\ts_barrier" ::: "memory");
    if (st) STG(nb, 0, pA + kk);
#pragma unroll
    for (int mi = 0; mi < 4; mi++)
#pragma unroll
      for (int ks = 0; ks < 2; ks++)
        afr[mi][ks] = *(const bf16x8*)(Lc + abase + mi * 1024 + ((((ks << 2) + kgrp) ^ sw) << 3));
#pragma unroll
    for (int nj = 0; nj < 2; nj++)
#pragma unroll
      for (int ks = 0; ks < 2; ks++)
        bfr[0][nj][ks] = *(const bf16x8*)(Lc + 8192 + bbase + nj * 1024 + ((((ks << 2) + kgrp) ^ sw) << 3));
    __builtin_amdgcn_s_setprio(1);
#pragma unroll
    for (int mi = 0; mi < 4; mi++)
#pragma unroll
      for (int nj = 0; nj < 2; nj++)
#pragma unroll
        for (int ks = 0; ks < 2; ks++)
          acc[mi][nj] = __builtin_amdgcn_mfma_f32_16x16x32_bf16(afr[mi][ks], bfr[0][nj][ks], acc[mi][nj], 0, 0, 0);
    __builtin_amdgcn_s_setprio(0);

    // ---------- phase 1: quadrant (qm0, qn1) ----------
    if (st) {
      asm volatile("s_waitcnt vmcnt(4)\n\ts_barrier" ::: "memory");
      STG(nb, 1, pB + kk);
    } else {
      asm volatile("s_waitcnt vmcnt(2)\n\ts_barrier" ::: "memory");
    }
#pragma unroll
    for (int nj = 0; nj < 2; nj++)
#pragma unroll
      for (int ks = 0; ks < 2; ks++)
        bfr[1][nj][ks] = *(const bf16x8*)(Lc + 16384 + bbase + nj * 1024 + ((((ks << 2) + kgrp) ^ sw) << 3));
    __builtin_amdgcn_s_setprio(1);
#pragma unroll
    for (int mi = 0; mi < 4; mi++)
#pragma unroll
      for (int nj = 0; nj < 2; nj++)
#pragma unroll
        for (int ks = 0; ks < 2; ks++)
          acc[mi][2 + nj] = __builtin_amdgcn_mfma_f32_16x16x32_bf16(afr[mi][ks], bfr[1][nj][ks], acc[mi][2 + nj], 0, 0, 0);
    __builtin_amdgcn_s_setprio(0);

    // ---------- phase 2: quadrant (qm1, qn1) ----------
    if (st) {
      asm volatile("s_waitcnt vmcnt(4)\n\ts_barrier" ::: "memory");
      STG(nb, 2, pB + (size_t)32 * K + kk);
    } else {
      asm volatile("s_waitcnt vmcnt(0)\n\ts_barrier" ::: "memory");
    }
#pragma unroll
    for (int mi = 0; mi < 4; mi++)
#pragma unroll
      for (int ks = 0; ks < 2; ks++)
        afr[mi][ks] = *(const bf16x8*)(Lc + 24576 + abase + mi * 1024 + ((((ks << 2) + kgrp) ^ sw) << 3));
    __builtin_amdgcn_s_setprio(1);
#pragma unroll
    for (int mi = 0; mi < 4; mi++)
#pragma unroll
      for (int nj = 0; nj < 2; nj++)
#pragma unroll
        for (int ks = 0; ks < 2; ks++)
          acc[4 + mi][2 + nj] = __builtin_amdgcn_mfma_f32_16x16x32_bf16(afr[mi][ks], bfr[1][nj][ks], acc[4 + mi][2 + nj], 0, 0, 0);
    __builtin_amdgcn_s_setprio(0);

    // ---------- phase 3: quadrant (qm1, qn0) ----------
    if (st) {
      asm volatile("s_waitcnt vmcnt(4)\n\ts_barrier" ::: "memory");
      STG(nb, 3, pA + (size_t)64 * K + kk);
    } else {
      asm volatile("s_barrier" ::: "memory");
    }
    __builtin_amdgcn_s_setprio(1);
#pragma unroll
    for (int mi = 0; mi < 4; mi++)
#pragma unroll
      for (int nj = 0; nj < 2; nj++)
#pragma unroll
        for (int ks = 0; ks < 2; ks++)
          acc[4 + mi][nj] = __builtin_amdgcn_mfma_f32_16x16x32_bf16(afr[mi][ks], bfr[0][nj][ks], acc[4 + mi][nj], 0, 0, 0);
    __builtin_amdgcn_s_setprio(0);
  }
#undef STG

  // ---------- epilogue ----------
#pragma unroll
  for (int MI = 0; MI < 8; MI++) {
#pragma unroll
    for (int NJ = 0; NJ < 4; NJ++) {
      const int gr = m0 + wr * 128 + MI * 16 + kgrp * 4;
      const int gc = n0 + wc * 64 + NJ * 16 + row16;
      const float bv = bias[gc];
#pragma unroll
      for (int jj = 0; jj < 4; jj++) {
        float v = acc[MI][NJ][jj] + bv;
        if (OUTF) ((float*)C)[(size_t)(gr + jj) * N + gc] = v;
        else ((unsigned short*)C)[(size_t)(gr + jj) * N + gc] = f2bf(v);
      }
    }
  }
}

// ---------------- RoPE (interleaved), in-place on bf16, row stride ld ----------------
__global__ void rope_kernel(unsigned short* __restrict__ X,
                            const int* __restrict__ pos_ids,
                            int ncols, int ld) {
  const int perrow = ncols >> 3;
  int idx = blockIdx.x * 256 + threadIdx.x;
  const int row = idx / perrow;
  const int c0 = (idx - row * perrow) << 3;
  const float pos = (float)pos_ids[row];
  unsigned short* p = X + (size_t)row * ld + c0;
  uint4 v = *(uint4*)p;
  unsigned short* e = (unsigned short*)&v;
  const int p0 = (c0 & 127) >> 1;
#pragma unroll
  for (int q = 0; q < 4; ++q) {
    const float inv = exp2f(-(float)(p0 + q) * (19.931568569324174f / 64.f));
    const float fr = pos * inv;
    float sn, cs;
    __sincosf(fr, &sn, &cs);
    const float xe = bf2f(e[2 * q]);
    const float xo = bf2f(e[2 * q + 1]);
    e[2 * q]     = f2bf(xe * cs - xo * sn);
    e[2 * q + 1] = f2bf(xo * cs + xe * sn);
  }
  *(uint4*)p = v;
}

// ---------------- V transpose: V[m, n] (stride ldv) -> Vt[b*1024 + n][m % 2048] ----------------
__global__ void transpose_v(const unsigned short* __restrict__ V, int ldv,
                            unsigned short* __restrict__ Vt) {
  __shared__ unsigned short tile[32][40];
  const int t = threadIdx.x;
  const int n0 = blockIdx.x * 32;   // V col (0..1023)
  const int m0 = blockIdx.y * 32;   // V row (0..4095)
  const int r = t >> 3;
  const int c = (t & 7) << 2;
  const unsigned short* src = V + (size_t)(m0 + r) * ldv + n0 + c;
  ushort4 d = *(const ushort4*)src;
  tile[r][c] = d.x; tile[r][c + 1] = d.y; tile[r][c + 2] = d.z; tile[r][c + 3] = d.w;
  __syncthreads();
  const int b = m0 >> 11;
  unsigned short* dst = Vt + (size_t)(b * 1024 + n0 + r) * 2048 + (m0 & 2047) + c;
  ushort4 o;
  o.x = tile[c][r]; o.y = tile[c + 1][r]; o.z = tile[c + 2][r]; o.w = tile[c + 3][r];
  *(ushort4*)dst = o;
}

// ---------------- causal GQA flash attention, 8-wave 32x32, swapped QK^T ----------------
__global__ __launch_bounds__(512, 2)
void attn_kernel2(const unsigned short* __restrict__ QKV,
                  const unsigned short* __restrict__ Vt,
                  unsigned short* __restrict__ O) {
  __shared__ unsigned short sK[2][64 * 128];
  __shared__ unsigned short sV[2][128 * 64];

  const int t = threadIdx.x;
  const int lane = t & 63;
  const int w = t >> 6;
  const int l31 = lane & 31;
  const int hi = lane >> 5;
  const int qt = 7 - blockIdx.x;          // heavy tiles dispatch first
  const int bh = blockIdx.y;
  const int b = bh >> 5, h = bh & 31;
  const int kh = h >> 2;                  // n_rep = 4 (repeat_interleave)
  const int q0 = qt * 256;
  const int qw = q0 + w * 32;
  const int qg = qw + l31;                // this lane's q row (softmax state owner)

  const int ntiles = (q0 + 256) >> 6;     // 4qt+4
  const int myTiles = (qw + 95) >> 6;     // ceil((qw+32)/64)

  // ---- staging geometry (pre-swizzled global source, linear LDS dest) ----
  const int krow0 = t >> 4;               // 0..31 (pass2: +32)
  const int kslot = t & 15;
  const int vrow0 = t >> 3;               // 0..63 (pass2: +64)
  const int vslot = t & 7;
  const unsigned short* Kp = QKV + (size_t)(b * S_LEN) * LDQKV + 4096 + kh * HDIM;
  const unsigned short* Vp = Vt + (size_t)(b * 1024 + kh * HDIM) * 2048;
  const int ksw = (kslot ^ (krow0 & 7)) << 3;
  const int vsw = (vslot ^ (vrow0 & 7)) << 3;
  const unsigned short* KpA = Kp + (size_t)krow0 * LDQKV + ksw;
  const unsigned short* KpB = Kp + (size_t)(krow0 + 32) * LDQKV + ksw;
  const unsigned short* VpA = Vp + (size_t)vrow0 * 2048 + vsw;
  const unsigned short* VpB = Vp + (size_t)(vrow0 + 64) * 2048 + vsw;

#define STAGE(bufi, kv0m)                                              \
  {                                                                    \
    gload16(KpA + (size_t)(kv0m)*LDQKV, &sK[bufi][t * 8]);             \
    gload16(KpB + (size_t)(kv0m)*LDQKV, &sK[bufi][4096 + t * 8]);      \
    gload16(VpA + (kv0m), &sV[bufi][t * 8]);                           \
    gload16(VpB + (kv0m), &sV[bufi][4096 + t * 8]);                    \
  }

  // ---- Q fragments (hoisted; B-operand of swapped QK^T) ----
  bf16x8 qf[8];
  {
    const unsigned short* qb = QKV + (size_t)(b * S_LEN + qw + l31) * LDQKV + h * HDIM + hi * 8;
#pragma unroll
    for (int kd = 0; kd < 8; kd++) qf[kd] = *(const bf16x8*)(qb + kd * 16);
  }

  f32x16 o[4];
#pragma unroll
  for (int nt = 0; nt < 4; nt++)
#pragma unroll
    for (int r = 0; r < 16; r++) o[nt][r] = 0.f;
  float m = -1e30f, lsum = 0.f;

  const int rw7 = (l31 & 7) << 4;          // byte-swizzle field for LDS reads
  const int kswz = (hi << 4) ^ rw7;        // combines hi-halfword select with row swizzle
  const int kbase0 = l31 * 128;            // ushort offsets (row stride 128 us = 256B)
  const int vbase = l31 * 64;              // sV row stride 64 us = 128B

  STAGE(0, 0);
  int buf = 0;
  for (int it = 0; it < ntiles; ++it) {
    if (it + 1 < ntiles) {
      STAGE(buf ^ 1, (it + 1) << 6);
      asm volatile("s_waitcnt vmcnt(4)" ::: "memory");
    } else {
      asm volatile("s_waitcnt vmcnt(0)" ::: "memory");
    }
    __builtin_amdgcn_s_barrier();

    if (it < myTiles) {
      const unsigned short* sKc = &sK[buf][0];
      const unsigned short* sVc = &sV[buf][0];
      const int kv0 = it << 6;

      // ---- QK^T (swapped): st[s][r] = S[q=qg][kv = kv0+32s+crow(r,hi)] ----
      f32x16 st[2];
#pragma unroll
      for (int r = 0; r < 16; r++) { st[0][r] = 0.f; st[1][r] = 0.f; }
      __builtin_amdgcn_s_setprio(1);
#pragma unroll
      for (int kd = 0; kd < 8; kd++) {
        bf16x8 k0 = *(const bf16x8*)(sKc + kbase0 + (((kd << 5) ^ kswz) >> 1));
        bf16x8 k1 = *(const bf16x8*)(sKc + 4096 + kbase0 + (((kd << 5) ^ kswz) >> 1));
        st[0] = __builtin_amdgcn_mfma_f32_32x32x16_bf16(k0, qf[kd], st[0], 0, 0, 0);
        st[1] = __builtin_amdgcn_mfma_f32_32x32x16_bf16(k1, qf[kd], st[1], 0, 0, 0);
      }
      __builtin_amdgcn_s_setprio(0);

      // ---- causal mask (diagonal tile only) ----
      if (it == myTiles - 1) {
#pragma unroll
        for (int s2 = 0; s2 < 2; s2++)
#pragma unroll
          for (int r = 0; r < 16; r++) {
            const int kvg = kv0 + s2 * 32 + (r & 3) + 8 * (r >> 2) + 4 * hi;
            if (kvg > qg) st[s2][r] = -1e30f;
          }
      }

      // ---- tile max (lane-local + cross-half shfl) ----
      float tmax = st[0][0];
#pragma unroll
      for (int r = 1; r < 16; r++) tmax = fmaxf(tmax, st[0][r]);
#pragma unroll
      for (int r = 0; r < 16; r++) tmax = fmaxf(tmax, st[1][r]);
      tmax = fmaxf(tmax, __shfl_xor(tmax, 32));

      // ---- defer-max rescale (T13) ----
      if (!__all(tmax <= m + THR_RAW)) {
        const float mnew = fmaxf(m, tmax);
        const float corr = exp2f((m - mnew) * C_LOG2);
        lsum *= corr;
#pragma unroll
        for (int r = 0; r < 16; r++) {
          const int src = (r & 3) + 8 * (r >> 2) + 4 * hi;
          const float cr = __shfl(corr, src);
#pragma unroll
          for (int nt = 0; nt < 4; nt++) o[nt][r] *= cr;
        }
        m = mnew;
      }
      const float mC = m * C_LOG2;

      // ---- exp + row sum (cross-half shfl) ----
#pragma unroll
      for (int s2 = 0; s2 < 2; s2++)
#pragma unroll
        for (int r = 0; r < 16; r++) st[s2][r] = exp2f(fmaf(st[s2][r], C_LOG2, -mC));
      float tsum = st[0][0];
#pragma unroll
      for (int r = 1; r < 16; r++) tsum += st[0][r];
#pragma unroll
      for (int r = 0; r < 16; r++) tsum += st[1][r];
      tsum += __shfl_xor(tsum, 32);
      lsum += tsum;

      // ---- P -> bf16 A-fragments (cvt_pk + cross-half shfl_xor redistribution) ----
      bf16x8 pa[4];
#pragma unroll
      for (int s2 = 0; s2 < 2; s2++) {
        unsigned pw[8];
#pragma unroll
        for (int i = 0; i < 8; i++)
          asm("v_cvt_pk_bf16_f32 %0, %1, %2" : "=v"(pw[i]) : "v"(st[s2][2 * i]), "v"(st[s2][2 * i + 1]));
        const unsigned x0 = (unsigned)__shfl_xor((int)pw[0], 32);
        const unsigned x1 = (unsigned)__shfl_xor((int)pw[1], 32);
        const unsigned x2 = (unsigned)__shfl_xor((int)pw[2], 32);
        const unsigned x3 = (unsigned)__shfl_xor((int)pw[3], 32);
        const unsigned x4 = (unsigned)__shfl_xor((int)pw[4], 32);
        const unsigned x5 = (unsigned)__shfl_xor((int)pw[5], 32);
        const unsigned x6 = (unsigned)__shfl_xor((int)pw[6], 32);
        const unsigned x7 = (unsigned)__shfl_xor((int)pw[7], 32);
        union { unsigned u[4]; bf16x8 v; } u0, u1;
        u0.u[0] = hi ? x2 : pw[0];
        u0.u[1] = hi ? x3 : pw[1];
        u0.u[2] = hi ? pw[2] : x0;
        u0.u[3] = hi ? pw[3] : x1;
        u1.u[0] = hi ? x6 : pw[4];
        u1.u[1] = hi ? x7 : pw[5];
        u1.u[2] = hi ? pw[6] : x4;
        u1.u[3] = hi ? pw[7] : x5;
        pa[2 * s2] = u0.v; pa[2 * s2 + 1] = u1.v;
      }

      // ---- PV: o[nt] += P @ V ----
      __builtin_amdgcn_s_setprio(1);
#pragma unroll
      for (int nt = 0; nt < 4; nt++) {
        const unsigned short* vr = sVc + vbase + nt * 2048;  // (nt*32 rows)*64
#pragma unroll
        for (int ks = 0; ks < 4; ks++) {
          bf16x8 vb = *(const bf16x8*)(vr + (((ks << 5) ^ kswz) >> 1));
          o[nt] = __builtin_amdgcn_mfma_f32_32x32x16_bf16(pa[ks], vb, o[nt], 0, 0, 0);
        }
      }
      __builtin_amdgcn_s_setprio(0);
    }

    asm volatile("" ::: "memory");
    __builtin_amdgcn_s_barrier();
    buf ^= 1;
  }

  // ---- epilogue: normalize (cross-lane linv via shfl), write bf16 ----
  const float linv = 1.0f / lsum;
#pragma unroll
  for (int r = 0; r < 16; r++) {
    const int qr = (r & 3) + 8 * (r >> 2) + 4 * hi;
    const float lr = __shfl(linv, qr);
    unsigned short* orow = O + (size_t)(b * S_LEN + qw + qr) * 4096 + h * HDIM + l31;
#pragma unroll
    for (int nt = 0; nt < 4; nt++) orow[nt * 32] = f2bf(o[nt][r] * lr);
  }
#undef STAGE
}

// ---------------- launch ----------------
extern "C" void kernel_launch(void* const* d_in, const int* in_sizes, int n_in,
                              void* d_out, int out_size, void* d_ws, size_t ws_size,
                              hipStream_t stream) {
  const float* hs = (const float*)d_in[0];
  const int*  pos = (const int*)d_in[1];
  const float* Wq = (const float*)d_in[2];
  const float* bq = (const float*)d_in[3];
  const float* Wk = (const float*)d_in[4];
  const float* bk = (const float*)d_in[5];
  const float* Wv = (const float*)d_in[6];
  const float* bv = (const float*)d_in[7];
  const float* Wo = (const float*)d_in[8];
  const float* bo = (const float*)d_in[9];
  float* out = (float*)d_out;

  char* ws = (char*)d_ws;
  unsigned short* hbf  = (unsigned short*)(ws);               // hidden bf16; later attn_out
  unsigned short* Wbuf = (unsigned short*)(ws + 33554432);    // Wqkv bf16; later Wo
  unsigned short* QKV  = (unsigned short*)(ws + 83886080);    // [4096][6144]
  unsigned short* Vtb  = (unsigned short*)(ws + 134217728);   // [2048][2048]
  float*          biasb= (float*)(ws + 142606336);            // 6144 floats

  // 1. casts (hidden + fused QKV weights, contiguous)
  cast_f32_bf16<<<2048, 256, 0, stream>>>((const float4*)hs, (ushort4*)hbf, 4194304);
  cast_f32_bf16<<<2048, 256, 0, stream>>>((const float4*)Wq, (ushort4*)Wbuf, 4194304);
  cast_f32_bf16<<<1024, 256, 0, stream>>>((const float4*)Wk, (ushort4*)(Wbuf + 16777216), 1048576);
  cast_f32_bf16<<<1024, 256, 0, stream>>>((const float4*)Wv, (ushort4*)(Wbuf + 20971520), 1048576);
  hipMemcpyAsync(biasb, bq, 4096 * 4, hipMemcpyDeviceToDevice, stream);
  hipMemcpyAsync(biasb + 4096, bk, 1024 * 4, hipMemcpyDeviceToDevice, stream);
  hipMemcpyAsync(biasb + 5120, bv, 1024 * 4, hipMemcpyDeviceToDevice, stream);

  // 2. fused QKV projection: [4096,6144] (256^2 tiles, 4-phase pipeline)
  gemm256<0><<<dim3(24, 16), 512, 0, stream>>>(hbf, Wbuf, biasb, QKV, MROWS, LDQKV, 4096);

  // 3. Wo cast into Wbuf (Wqkv no longer needed)
  cast_f32_bf16<<<2048, 256, 0, stream>>>((const float4*)Wo, (ushort4*)Wbuf, 4194304);

  // 4. RoPE on Q (cols 0..4095) and K (cols 4096..5119)
  rope_kernel<<<8192, 256, 0, stream>>>(QKV, pos, 4096, LDQKV);
  rope_kernel<<<2048, 256, 0, stream>>>(QKV + 4096, pos, 1024, LDQKV);

  // 5. V transpose (cols 5120..6143) -> Vt[2048][2048]
  transpose_v<<<dim3(32, 128), 256, 0, stream>>>(QKV + 5120, LDQKV, Vtb);

  // 6. causal GQA flash attention (8-wave 32x32, swapped-QK^T) -> hbf
  attn_kernel2<<<dim3(8, 64), 512, 0, stream>>>(QKV, Vtb, hbf);

  // 7. output projection -> fp32 d_out
  gemm256<1><<<dim3(16, 16), 512, 0, stream>>>(hbf, Wbuf, bo, out, MROWS, 4096, 4096);
}